// Round 3
// baseline (50.022 us; speedup 1.0000x reference)
//
#include <hip/hip_runtime.h>
#include <math.h>

#define DD 512
#define BB 128
#define MM 1024
#define MARGIN 9.0f
#define EPSF 1e-6f
#define SPLIT 16  // blocks per head row; block covers 64 m's, wave covers 16

// Issue 8 coalesced float4 gathers (4 tail rows) into named regs.
#define ISSUE(P0, P1, P2, P3, P4, P5, P6, P7, iv)                             \
  do {                                                                        \
    const float4* ta_ = (const float4*)(emb + (size_t)(iv).x * DD) + 2 * lane;\
    const float4* tb_ = (const float4*)(emb + (size_t)(iv).y * DD) + 2 * lane;\
    const float4* tc_ = (const float4*)(emb + (size_t)(iv).z * DD) + 2 * lane;\
    const float4* td_ = (const float4*)(emb + (size_t)(iv).w * DD) + 2 * lane;\
    P0 = ta_[0]; P1 = ta_[1];                                                 \
    P2 = tb_[0]; P3 = tb_[1];                                                 \
    P4 = tc_[0]; P5 = tc_[1];                                                 \
    P6 = td_[0]; P7 = td_[1];                                                 \
  } while (0)

// Distances for 4 m's from a loaded buffer; reduce; lane0 stores float4.
#define COMPUTE4(P0, P1, P2, P3, P4, P5, P6, P7, iv, off)                     \
  do {                                                                        \
    float bt0_ = bias_tail[(iv).x], bt1_ = bias_tail[(iv).y];                 \
    float bt2_ = bias_tail[(iv).z], bt3_ = bias_tail[(iv).w];                 \
    float d_, ra_, rb_, rc_, rd_;                                             \
    d_ = h0.x - P0.x; ra_ = d_ * d_;                                          \
    d_ = h0.y - P0.y; ra_ += d_ * d_;                                         \
    d_ = h0.z - P0.z; ra_ += d_ * d_;                                         \
    d_ = h0.w - P0.w; ra_ += d_ * d_;                                         \
    d_ = h1.x - P1.x; ra_ += d_ * d_;                                         \
    d_ = h1.y - P1.y; ra_ += d_ * d_;                                         \
    d_ = h1.z - P1.z; ra_ += d_ * d_;                                         \
    d_ = h1.w - P1.w; ra_ += d_ * d_;                                         \
    d_ = h0.x - P2.x; rb_ = d_ * d_;                                          \
    d_ = h0.y - P2.y; rb_ += d_ * d_;                                         \
    d_ = h0.z - P2.z; rb_ += d_ * d_;                                         \
    d_ = h0.w - P2.w; rb_ += d_ * d_;                                         \
    d_ = h1.x - P3.x; rb_ += d_ * d_;                                         \
    d_ = h1.y - P3.y; rb_ += d_ * d_;                                         \
    d_ = h1.z - P3.z; rb_ += d_ * d_;                                         \
    d_ = h1.w - P3.w; rb_ += d_ * d_;                                         \
    d_ = h0.x - P4.x; rc_ = d_ * d_;                                          \
    d_ = h0.y - P4.y; rc_ += d_ * d_;                                         \
    d_ = h0.z - P4.z; rc_ += d_ * d_;                                         \
    d_ = h0.w - P4.w; rc_ += d_ * d_;                                         \
    d_ = h1.x - P5.x; rc_ += d_ * d_;                                         \
    d_ = h1.y - P5.y; rc_ += d_ * d_;                                         \
    d_ = h1.z - P5.z; rc_ += d_ * d_;                                         \
    d_ = h1.w - P5.w; rc_ += d_ * d_;                                         \
    d_ = h0.x - P6.x; rd_ = d_ * d_;                                          \
    d_ = h0.y - P6.y; rd_ += d_ * d_;                                         \
    d_ = h0.z - P6.z; rd_ += d_ * d_;                                         \
    d_ = h0.w - P6.w; rd_ += d_ * d_;                                         \
    d_ = h1.x - P7.x; rd_ += d_ * d_;                                         \
    d_ = h1.y - P7.y; rd_ += d_ * d_;                                         \
    d_ = h1.z - P7.z; rd_ += d_ * d_;                                         \
    d_ = h1.w - P7.w; rd_ += d_ * d_;                                         \
    _Pragma("unroll")                                                         \
    for (int o_ = 32; o_; o_ >>= 1) {                                         \
      ra_ += __shfl_xor(ra_, o_, 64);                                         \
      rb_ += __shfl_xor(rb_, o_, 64);                                         \
      rc_ += __shfl_xor(rc_, o_, 64);                                         \
      rd_ += __shfl_xor(rd_, o_, 64);                                         \
    }                                                                         \
    if (lane == 0) {                                                          \
      float4 q_;                                                              \
      q_.x = bh - sqrtf(ra_) + bt0_;                                          \
      q_.y = bh - sqrtf(rb_) + bt1_;                                          \
      q_.z = bh - sqrtf(rc_) + bt2_;                                          \
      q_.w = bh - sqrtf(rd_) + bt3_;                                          \
      *(float4*)(out + b * MM + mbase + (off)) = q_;                          \
    }                                                                         \
  } while (0)

__global__ __launch_bounds__(256, 4) void roth_fused_kernel(
    const int* __restrict__ u_idx,
    const int* __restrict__ r_idx,
    const int* __restrict__ v_idx,
    const float* __restrict__ emb,
    const float* __restrict__ rrot,
    const float* __restrict__ rcen,
    const float* __restrict__ rtrans,
    const float* __restrict__ bias_head,
    const float* __restrict__ bias_tail,
    float* __restrict__ out) {
  const int b = blockIdx.x / SPLIT;
  const int s = blockIdx.x % SPLIT;
  const int wid = threadIdx.x >> 6;
  const int lane = threadIdx.x & 63;
  const int u = u_idx[b];
  const int r = r_idx[b];

  // ---- head/relation row loads (issued first; L2/L3-hot after warmup) ----
  const float4* hrow = (const float4*)(emb + (size_t)u * DD);
  float4 hh0 = hrow[2 * lane];
  float4 hh1 = hrow[2 * lane + 1];
  const float4* grow = (const float4*)(rrot + (size_t)r * DD);
  const float4* crow = (const float4*)(rcen + (size_t)r * DD);
  const float4* trow = (const float4*)(rtrans + (size_t)r * DD);
  float4 g0 = grow[2 * lane], g1 = grow[2 * lane + 1];
  float4 c0 = crow[2 * lane], c1 = crow[2 * lane + 1];
  float4 t0 = trow[2 * lane], t1 = trow[2 * lane + 1];

  // ---- wave-uniform tail indices ----
  const int mbase = s * (MM / SPLIT) + wid * 16;
  const int4* vp = (const int4*)(v_idx + b * MM + mbase);
  const int4 i0 = vp[0], i1 = vp[1], i2 = vp[2], i3 = vp[3];

  // ---- pipeline prologue: 16 gathers in flight before head VALU work ----
  float4 A0, A1, A2, A3, A4, A5, A6, A7;
  float4 B0, B1, B2, B3, B4, B5, B6, B7;
  ISSUE(A0, A1, A2, A3, A4, A5, A6, A7, i0);
  ISSUE(B0, B1, B2, B3, B4, B5, B6, B7, i1);

  // ---- head transform (overlaps the in-flight gathers) ----
  float ss = hh0.x * hh0.x + hh0.y * hh0.y + hh0.z * hh0.z + hh0.w * hh0.w +
             hh1.x * hh1.x + hh1.y * hh1.y + hh1.z * hh1.z + hh1.w * hh1.w;
#pragma unroll
  for (int o = 32; o; o >>= 1) ss += __shfl_xor(ss, o, 64);
  float un = fmaxf(sqrtf(ss), 1e-15f);
  float scale = tanhf(un) / un;  // sqrt_c = 1

  float4 x0, x1;
  x0.x = hh0.x * scale + c0.x; x0.y = hh0.y * scale + c0.y;
  x0.z = hh0.z * scale + c0.z; x0.w = hh0.w * scale + c0.w;
  x1.x = hh1.x * scale + c1.x; x1.y = hh1.y * scale + c1.y;
  x1.z = hh1.z * scale + c1.z; x1.w = hh1.w * scale + c1.w;

  float4 h0, h1;  // transformed head, +EPS folded
  {
    float gn = fmaxf(sqrtf(g0.x * g0.x + g0.y * g0.y), 1e-15f);
    float cc = g0.x / gn, sn = g0.y / gn;
    h0.x = cc * x0.x - sn * x0.y;
    h0.y = cc * x0.y + sn * x0.x;
  }
  {
    float gn = fmaxf(sqrtf(g0.z * g0.z + g0.w * g0.w), 1e-15f);
    float cc = g0.z / gn, sn = g0.w / gn;
    h0.z = cc * x0.z - sn * x0.w;
    h0.w = cc * x0.w + sn * x0.z;
  }
  {
    float gn = fmaxf(sqrtf(g1.x * g1.x + g1.y * g1.y), 1e-15f);
    float cc = g1.x / gn, sn = g1.y / gn;
    h1.x = cc * x1.x - sn * x1.y;
    h1.y = cc * x1.y + sn * x1.x;
  }
  {
    float gn = fmaxf(sqrtf(g1.z * g1.z + g1.w * g1.w), 1e-15f);
    float cc = g1.z / gn, sn = g1.w / gn;
    h1.z = cc * x1.z - sn * x1.w;
    h1.w = cc * x1.w + sn * x1.z;
  }
  h0.x = h0.x - c0.x + t0.x + EPSF; h0.y = h0.y - c0.y + t0.y + EPSF;
  h0.z = h0.z - c0.z + t0.z + EPSF; h0.w = h0.w - c0.w + t0.w + EPSF;
  h1.x = h1.x - c1.x + t1.x + EPSF; h1.y = h1.y - c1.y + t1.y + EPSF;
  h1.z = h1.z - c1.z + t1.z + EPSF; h1.w = h1.w - c1.w + t1.w + EPSF;

  const float bh = MARGIN + bias_head[u];

  // ---- steady state: compute group k while group k+1/k+2 loads in flight --
  COMPUTE4(A0, A1, A2, A3, A4, A5, A6, A7, i0, 0);
  ISSUE(A0, A1, A2, A3, A4, A5, A6, A7, i2);
  COMPUTE4(B0, B1, B2, B3, B4, B5, B6, B7, i1, 4);
  ISSUE(B0, B1, B2, B3, B4, B5, B6, B7, i3);
  COMPUTE4(A0, A1, A2, A3, A4, A5, A6, A7, i2, 8);
  COMPUTE4(B0, B1, B2, B3, B4, B5, B6, B7, i3, 12);
}

extern "C" void kernel_launch(void* const* d_in, const int* in_sizes, int n_in,
                              void* d_out, int out_size, void* d_ws, size_t ws_size,
                              hipStream_t stream) {
  const int* u_idx = (const int*)d_in[0];
  const int* r_idx = (const int*)d_in[1];
  const int* v_idx = (const int*)d_in[2];
  const float* emb = (const float*)d_in[3];
  const float* rrot = (const float*)d_in[4];
  const float* rcen = (const float*)d_in[5];
  const float* rtrans = (const float*)d_in[6];
  const float* bias_head = (const float*)d_in[7];
  const float* bias_tail = (const float*)d_in[8];
  float* out = (float*)d_out;

  roth_fused_kernel<<<BB * SPLIT, 256, 0, stream>>>(
      u_idx, r_idx, v_idx, emb, rrot, rcen, rtrans, bias_head, bias_tail, out);
}